// Round 7
// baseline (39660.791 us; speedup 1.0000x reference)
//
#include <hip/hip_runtime.h>
#include <stdint.h>

// ---------------- problem constants ----------------
#define TN    2048      // time steps
#define NBLK  128       // 4 groups x 32 merged-role blocks

// Each block: 16 cell-1 columns (S1) + 16 cell-2 columns (S2) of one 64-row
// batch tile. 4 waves x 16 rows each (wave owns rows; no duplicate A loads,
// no inter-wave gate exchange).
//
// LDS layout (bf16, pad strides == 6 mod 32 words -> ~2-way bank aliasing):
//  wlds1   [48][524]   cell1 W_hh1 rows (r,z,n x 16 cols), K=512   50304 B
//  wlds2rz [32][1036]  cell2 r,z rows, K=1024 = [W_ih2 | W_hh2]    66304 B
//  wlds2n  [32][524]   cell2 in_ (t=0) / hn (t=1) rows, K=512      33536 B
//  sx      u16 [64][16]  store-repack buffer                        2048 B
//  fmisc   f32 [272]   gate scalars                                 1088 B
#define W1STRIDE 524
#define RZSTRIDE 1036
#define NSTRIDE  524
#define W2RZ_OFF 25152          // elems: 48*524
#define W2N_OFF  58304          // elems: W2RZ_OFF + 32*1036
#define SX_OFF   150144         // bytes
#define FMISC_OFF 152192        // bytes
#define SMEM_BYTES 153600

// ws layout:
//   0       : h0x bf16 [4 slots][256][512]   (1 MiB)   slot(t)=t&3; t=-1 -> slot 3
//   1048576 : h1x bf16 [4 slots][256][512]   (1 MiB)
//   2097152 : counters; group g at byte g*256: u32 P1 (+0), u32 P2 (+4)
#define H0_OFF  0
#define H1_OFF  1048576
#define CNT_OFF 2097152

typedef __attribute__((ext_vector_type(8))) short bf16x8;
typedef __attribute__((ext_vector_type(4))) float f32x4;

__device__ __forceinline__ float sigf(float v)   { return 1.0f / (1.0f + __expf(-v)); }
__device__ __forceinline__ float tanhf_(float v) { return 2.0f / (1.0f + __expf(-2.0f * v)) - 1.0f; }
__device__ __forceinline__ unsigned short f2bf(float f) {
  unsigned u = __float_as_uint(f);
  u += 0x7fffu + ((u >> 16) & 1u);   // RNE
  return (unsigned short)(u >> 16);
}

// L2-bypassing (agent-scope, sc1) 16B fragment load from the IF coherence
// point -- no cache-maintenance op needed to observe remote writes.
__device__ __forceinline__ bf16x8 ld_coh16(const unsigned short* p) {
  union { unsigned long long q[2]; bf16x8 v; } u;
  u.q[0] = __hip_atomic_load((const unsigned long long*)p,
                             __ATOMIC_RELAXED, __HIP_MEMORY_SCOPE_AGENT);
  u.q[1] = __hip_atomic_load((const unsigned long long*)p + 1,
                             __ATOMIC_RELAXED, __HIP_MEMORY_SCOPE_AGENT);
  return u.v;
}

// Re-run safe init: state mirrors (slot 3), out = b_out, counters = 0.
extern "C" __global__ void gru_init(const float* __restrict__ h0,
                                    const float* __restrict__ h1,
                                    const float* __restrict__ b_out,
                                    float* __restrict__ out,
                                    char* __restrict__ ws) {
  int i = blockIdx.x * 256 + threadIdx.x;     // 512 blocks
  unsigned short* h0x = (unsigned short*)(ws + H0_OFF);
  unsigned short* h1x = (unsigned short*)(ws + H1_OFF);
  h0x[3 * 131072 + i] = f2bf(h0[i]);
  h1x[3 * 131072 + i] = f2bf(h1[i]);
  if (blockIdx.x == 0) out[threadIdx.x] = b_out[0];
  if (blockIdx.x == 1) ((unsigned*)(ws + CNT_OFF))[threadIdx.x] = 0u;  // covers 4*256B
}

extern "C" __global__ void __launch_bounds__(256, 1)
gru_main(const float* __restrict__ x,
         const float* __restrict__ W_ih1, const float* __restrict__ W_hh1,
         const float* __restrict__ b_ih1, const float* __restrict__ b_hh1,
         const float* __restrict__ W_ih2, const float* __restrict__ W_hh2,
         const float* __restrict__ b_ih2, const float* __restrict__ b_hh2,
         const float* __restrict__ W_out, const float* __restrict__ b_out,
         const float* __restrict__ h0in, const float* __restrict__ h1in,
         float* __restrict__ out, char* __restrict__ ws)
{
  extern __shared__ char smem[];
  unsigned short* wlds1 = (unsigned short*)smem;
  unsigned short* w2rz  = (unsigned short*)smem + W2RZ_OFF;
  unsigned short* w2n   = (unsigned short*)smem + W2N_OFF;
  unsigned short* sxu   = (unsigned short*)(smem + SX_OFF);
  float* fmisc          = (float*)(smem + FMISC_OFF);

  unsigned short* h0x = (unsigned short*)(ws + H0_OFF);
  unsigned short* h1x = (unsigned short*)(ws + H1_OFF);

  const int bid = blockIdx.x, tid = threadIdx.x;
  const int wv = tid >> 6, l = tid & 63, l15 = l & 15, l4 = l >> 4;

  // XCD-aware grouping: group g = bids with bid%4==g -> XCDs {g, g+4}
  const int bt  = bid & 3;          // group = batch tile (64 rows)
  const int sub = bid >> 2;         // 0..31 within group
  const int S1 = sub * 16;          // owned cell-1 columns
  const int S2 = sub * 16;          // owned cell-2 columns

  unsigned* cnt = (unsigned*)(ws + CNT_OFF + bt * 256);   // P1 at +0, P2 at +4

  // ---------------- weight preload into LDS (bf16) ----------------
  // cell1: rows j = g*16+c -> W_hh1 gate-row g*512 + S1 + c, K=512
  for (int idx = tid; idx < 48 * 512; idx += 256) {
    int j = idx >> 9, kk = idx & 511;
    int g = j >> 4, c = j & 15;
    wlds1[j * W1STRIDE + kk] = f2bf(W_hh1[(g * 512 + S1 + c) * 512 + kk]);
  }
  // cell2 r/z: rows j = g2*16+c -> gate-row g2*512 + S2 + c, K=1024 [Wih2|Whh2]
  for (int idx = tid; idx < 32 * 1024; idx += 256) {
    int j = idx >> 10, kk = idx & 1023;
    int g2 = j >> 4, c = j & 15;
    float v = (kk < 512) ? W_ih2[(g2 * 512 + S2 + c) * 512 + kk]
                         : W_hh2[(g2 * 512 + S2 + c) * 512 + kk - 512];
    w2rz[j * RZSTRIDE + kk] = f2bf(v);
  }
  // cell2 n: rows j = t*16+c; t=0: in_ (W_ih2), t=1: hn (W_hh2); K=512
  for (int idx = tid; idx < 32 * 512; idx += 256) {
    int j = idx >> 9, kk = idx & 511;
    int t = j >> 4, c = j & 15;
    const float* Wsrc = t ? W_hh2 : W_ih2;
    w2n[j * NSTRIDE + kk] = f2bf(Wsrc[(1024 + S2 + c) * 512 + kk]);
  }
  // gate scalars
  if (tid < 48) {           // cell1: wi1 / bi1 / bh1 per gate-row
    int g = tid >> 4, c = tid & 15;
    int grow = g * 512 + S1 + c;
    fmisc[tid]      = W_ih1[grow];
    fmisc[48 + tid] = b_ih1[grow];
    fmisc[96 + tid] = b_hh1[grow];
  } else if (tid < 144) {   // cell2: 6 x 16 scalars at fmisc[144..239]
    int t = tid - 48;       // 0..95
    int g = t >> 4, c = t & 15;
    float v;
    if      (g == 0) v = b_ih2[S2 + c];
    else if (g == 1) v = b_ih2[512 + S2 + c];
    else if (g == 2) v = b_ih2[1024 + S2 + c];
    else if (g == 3) v = b_hh2[S2 + c];
    else if (g == 4) v = b_hh2[512 + S2 + c];
    else             v = b_hh2[1024 + S2 + c];
    fmisc[144 + t] = v;
  }
  __syncthreads();

  // ---------------- per-thread constants / carries ----------------
  int rowD[4];                       // D rows (reg-based), global batch rows
  #pragma unroll
  for (int q = 0; q < 4; ++q) rowD[q] = bt * 64 + wv * 16 + l4 * 4 + q;
  const int arow = (wv * 16 + l15) * 512;   // A-fragment row offset (lane&15)

  float c0[4], c1[4];                // fp32 carries: h0 (col S1+l15), h1 (col S2+l15)
  #pragma unroll
  for (int q = 0; q < 4; ++q) {
    c0[q] = h0in[rowD[q] * 512 + S1 + l15];
    c1[q] = h1in[rowD[q] * 512 + S2 + l15];
  }
  const float wout = W_out[S2 + l15];

  // cell1 gate scalars (per col l15)
  const float wir = fmisc[l15],      wiz = fmisc[16 + l15],  win = fmisc[32 + l15];
  const float bir = fmisc[48 + l15], biz = fmisc[64 + l15],  bin = fmisc[80 + l15];
  const float bhr = fmisc[96 + l15], bhz = fmisc[112 + l15], bhn = fmisc[128 + l15];
  // cell2 gate scalars
  const float bir2 = fmisc[144 + l15], biz2 = fmisc[160 + l15], bin2 = fmisc[176 + l15];
  const float bhr2 = fmisc[192 + l15], bhz2 = fmisc[208 + l15], bhn2 = fmisc[224 + l15];

  int dead = 0;   // only tid0's copy matters

  // coherent (IF-level, sc1) u64 store of repacked state
  auto st_coh = [&](unsigned short* p, unsigned long long v) {
    __hip_atomic_store((unsigned long long*)p, v, __ATOMIC_RELAXED, __HIP_MEMORY_SCOPE_AGENT);
  };

  // ---------------- tick loop ----------------
  for (int k = 0; k < TN; ++k) {
    // =================== phase 1: h0(k) = GRU1(x(k), h0(k-1)) ===================
    // h0(k-1) completeness was guaranteed by last tick's wait (P1 >= 32k).
    float xv[4];
    #pragma unroll
    for (int q = 0; q < 4; ++q) xv[q] = x[rowD[q] * 2048 + k];

    {
      f32x4 a1[3];
      #pragma unroll
      for (int g = 0; g < 3; ++g) a1[g] = f32x4{0.f, 0.f, 0.f, 0.f};

      const unsigned short* srcA = h0x + ((k + 3) & 3) * 131072 + bt * 32768;
      #pragma unroll 4
      for (int ks = 0; ks < 16; ++ks) {
        bf16x8 af = ld_coh16(srcA + arow + ks * 32 + l4 * 8);
        #pragma unroll
        for (int g = 0; g < 3; ++g) {
          bf16x8 bw = *(const bf16x8*)(wlds1 + (g * 16 + l15) * W1STRIDE + ks * 32 + l4 * 8);
          a1[g] = __builtin_amdgcn_mfma_f32_16x16x32_bf16(af, bw, a1[g], 0, 0, 0);
        }
      }
      #pragma unroll
      for (int q = 0; q < 4; ++q) {
        float rg = sigf(xv[q] * wir + bir + a1[0][q] + bhr);
        float zg = sigf(xv[q] * wiz + biz + a1[1][q] + bhz);
        float ng = tanhf_(xv[q] * win + bin + rg * (a1[2][q] + bhn));
        float hv = (1.0f - zg) * ng + zg * c0[q];
        c0[q] = hv;
        sxu[(wv * 16 + l4 * 4 + q) * 16 + l15] = f2bf(hv);   // repack
      }
    }
    __syncthreads();
    {
      unsigned long long v = ((const unsigned long long*)sxu)[tid];
      unsigned short* dst = h0x + (k & 3) * 131072
                          + (bt * 64 + (tid >> 2)) * 512 + S1 + (tid & 3) * 4;
      st_coh(dst, v);
    }
    asm volatile("s_waitcnt vmcnt(0)" ::: "memory");
    __syncthreads();
    if (tid == 0)
      __hip_atomic_fetch_add(cnt, 1u, __ATOMIC_RELAXED, __HIP_MEMORY_SCOPE_AGENT);  // P1

    // =================== single wait: all h0(k) + all h1(k-1) ===================
    if (tid == 0 && !dead) {
      unsigned tP1 = 32u * (unsigned)(k + 1), tP2 = 32u * (unsigned)k;
      int spins = 0;
      for (;;) {
        unsigned long long v = __hip_atomic_load((const unsigned long long*)cnt,
                                                 __ATOMIC_RELAXED, __HIP_MEMORY_SCOPE_AGENT);
        if ((unsigned)(v & 0xffffffffu) >= tP1 && (unsigned)(v >> 32) >= tP2) break;
        __builtin_amdgcn_s_sleep(2);
        if (++spins > 2000000) { dead = 1; break; }   // bounded failure, no hang
      }
    }
    __syncthreads();

    // =================== phase 2: h1(k) = GRU2(h0(k), h1(k-1)) ===================
    {
      f32x4 a2[4];   // r, z, in_, hn
      #pragma unroll
      for (int g = 0; g < 4; ++g) a2[g] = f32x4{0.f, 0.f, 0.f, 0.f};

      const unsigned short* s0 = h0x + (k & 3) * 131072 + bt * 32768;       // h0(k)
      const unsigned short* s1 = h1x + ((k + 3) & 3) * 131072 + bt * 32768; // h1(k-1)

      #pragma unroll 4
      for (int ks = 0; ks < 16; ++ks) {                 // K 0..511: h0(k) operand
        bf16x8 af = ld_coh16(s0 + arow + ks * 32 + l4 * 8);
        #pragma unroll
        for (int g2 = 0; g2 < 2; ++g2) {
          bf16x8 bw = *(const bf16x8*)(w2rz + (g2 * 16 + l15) * RZSTRIDE + ks * 32 + l4 * 8);
          a2[g2] = __builtin_amdgcn_mfma_f32_16x16x32_bf16(af, bw, a2[g2], 0, 0, 0);
        }
        bf16x8 bn = *(const bf16x8*)(w2n + l15 * NSTRIDE + ks * 32 + l4 * 8);
        a2[2] = __builtin_amdgcn_mfma_f32_16x16x32_bf16(af, bn, a2[2], 0, 0, 0);
      }
      #pragma unroll 4
      for (int ks = 16; ks < 32; ++ks) {                // K 512..1023: h1(k-1) operand
        bf16x8 af = ld_coh16(s1 + arow + (ks - 16) * 32 + l4 * 8);
        #pragma unroll
        for (int g2 = 0; g2 < 2; ++g2) {
          bf16x8 bw = *(const bf16x8*)(w2rz + (g2 * 16 + l15) * RZSTRIDE + ks * 32 + l4 * 8);
          a2[g2] = __builtin_amdgcn_mfma_f32_16x16x32_bf16(af, bw, a2[g2], 0, 0, 0);
        }
        bf16x8 bh = *(const bf16x8*)(w2n + (16 + l15) * NSTRIDE + (ks - 16) * 32 + l4 * 8);
        a2[3] = __builtin_amdgcn_mfma_f32_16x16x32_bf16(af, bh, a2[3], 0, 0, 0);
      }

      #pragma unroll
      for (int q = 0; q < 4; ++q) {
        float rg = sigf(a2[0][q] + bir2 + bhr2);
        float zg = sigf(a2[1][q] + biz2 + bhz2);
        float ng = tanhf_(a2[2][q] + bin2 + rg * (a2[3][q] + bhn2));
        float hv = (1.0f - zg) * ng + zg * c1[q];
        c1[q] = hv;
        sxu[(wv * 16 + l4 * 4 + q) * 16 + l15] = f2bf(hv);   // repack
        if (k == TN - 1) atomicAdd(&out[rowD[q]], hv * wout); // final projection
      }
    }
    __syncthreads();
    {
      unsigned long long v = ((const unsigned long long*)sxu)[tid];
      unsigned short* dst = h1x + (k & 3) * 131072
                          + (bt * 64 + (tid >> 2)) * 512 + S2 + (tid & 3) * 4;
      st_coh(dst, v);
    }
    asm volatile("s_waitcnt vmcnt(0)" ::: "memory");
    __syncthreads();
    if (tid == 0)
      __hip_atomic_fetch_add(cnt + 1, 1u, __ATOMIC_RELAXED, __HIP_MEMORY_SCOPE_AGENT);  // P2
  }
}

extern "C" void kernel_launch(void* const* d_in, const int* in_sizes, int n_in,
                              void* d_out, int out_size, void* d_ws, size_t ws_size,
                              hipStream_t stream) {
  const float* x     = (const float*)d_in[0];
  const float* h0in  = (const float*)d_in[1];
  const float* h1in  = (const float*)d_in[2];
  const float* W_ih1 = (const float*)d_in[3];
  const float* W_hh1 = (const float*)d_in[4];
  const float* b_ih1 = (const float*)d_in[5];
  const float* b_hh1 = (const float*)d_in[6];
  const float* W_ih2 = (const float*)d_in[7];
  const float* W_hh2 = (const float*)d_in[8];
  const float* b_ih2 = (const float*)d_in[9];
  const float* b_hh2 = (const float*)d_in[10];
  const float* W_out = (const float*)d_in[11];
  const float* b_out = (const float*)d_in[12];
  float* out = (float*)d_out;
  char* ws = (char*)d_ws;

  (void)in_sizes; (void)n_in; (void)out_size; (void)ws_size;

  hipFuncSetAttribute((const void*)gru_main,
                      hipFuncAttributeMaxDynamicSharedMemorySize, SMEM_BYTES);

  hipLaunchKernelGGL(gru_init, dim3(512), dim3(256), 0, stream,
                     h0in, h1in, b_out, out, ws);

  void* args[] = { (void*)&x,
                   (void*)&W_ih1, (void*)&W_hh1, (void*)&b_ih1, (void*)&b_hh1,
                   (void*)&W_ih2, (void*)&W_hh2, (void*)&b_ih2, (void*)&b_hh2,
                   (void*)&W_out, (void*)&b_out,
                   (void*)&h0in, (void*)&h1in,
                   (void*)&out, (void*)&ws };
  hipLaunchCooperativeKernel((const void*)gru_main, dim3(NBLK), dim3(256),
                             args, SMEM_BYTES, stream);
}